// Round 9
// baseline (195.764 us; speedup 1.0000x reference)
//
#include <hip/hip_runtime.h>
#include <math.h>

constexpr int B = 2, H = 320, W = 512, D = 64;
constexpr int HW = H * W;
constexpr int R = 10;            // BLOCK // 2
constexpr int SEG = 80;          // output rows per cost block
constexpr int NSEG = H / SEG;    // 4
constexpr int RS = 548;          // vsbuf row stride (words)
constexpr int QUADS = B * HW / 4;// 81920 pixel-quads
constexpr float EPS = 1e-12f;
constexpr unsigned KM = 0xFFFFFFC0u;  // key mask: drop 6 mantissa bits, pack d

// Normalize + pack into float4 planes (640 blocks x 128 thr for occupancy).
__global__ void k_norm(const float* __restrict__ x, const float* __restrict__ gt,
                       float4* __restrict__ nrm4) {
    int idx = blockIdx.x * 128 + threadIdx.x;        // over 2*B*HW/4 pixel-quads
    if (idx >= 2 * B * (HW / 4)) return;
    int t = idx / (B * (HW / 4));
    int rem = idx - t * (B * (HW / 4));
    int b = rem / (HW / 4);
    int hw4 = rem - b * (HW / 4);
    const float* p = (t == 0 ? x : gt) + (size_t)b * 6 * HW + 4 * hw4;
    float4 c[6];
#pragma unroll
    for (int ch = 0; ch < 6; ++ch) c[ch] = *(const float4*)(p + (size_t)ch * HW);
    float4* q = nrm4 + (size_t)(t * B + b) * 2 * HW + 4 * hw4;
    float4 o0[4], o1[4];
    const float* cf = (const float*)c;
#pragma unroll
    for (int k = 0; k < 4; ++k) {
        float v0 = cf[k], v1 = cf[4 + k], v2 = cf[8 + k];
        float v3 = cf[12 + k], v4 = cf[16 + k], v5 = cf[20 + k];
        float n1 = fmaxf(sqrtf(v0 * v0 + v1 * v1 + v2 * v2), EPS);
        float n2 = fmaxf(sqrtf(v3 * v3 + v4 * v4 + v5 * v5), EPS);
        o0[k] = make_float4(v0 / n1, v1 / n1, v2 / n1, 0.f);
        o1[k] = make_float4(v3 / n2, v4 / n2, v5 / n2, 0.f);
    }
#pragma unroll
    for (int k = 0; k < 4; ++k) { q[k] = o0[k]; q[HW + k] = o1[k]; }
}

// 21x21 box-filtered SAD cost (LDS diff ring + LDS vs snapshots, one barrier
// per 8-row superstep, double-buffered parity) with SOFTWARE-PIPELINED diff
// loads: superstep ss+1's 16 global loads issue before the barrier and are
// consumed next iteration (latency hides under phase 2 + barrier).
// FUSE: interleave full argmin of the COMPLETE cprev volume (640 px/block).
template<bool FUSE>
__global__ __launch_bounds__(512, 2) void k_cost(const float4* __restrict__ nrm4,
                                                 float* __restrict__ cost,
                                                 const float* __restrict__ cprev,
                                                 float* __restrict__ dprev, int t) {
    const int blk = blockIdx.x;
    const int combo = blk & 7;     // B*NSEG = 8 combos; pins (b,seg) to one XCD
    const int d = blk >> 3;
    const int b = combo >> 2;
    const int seg = combo & 3;
    const int w = threadIdx.x;
    const float4* L4 = nrm4 + (size_t)(t * B + b) * 2 * HW;
    const float4* R4 = L4 + HW;
    const bool val = (w >= d);
    const int wr = val ? (w - d) : 0;
    const int h0 = seg * SEG;

    __shared__ float ring[21][W];     // diff delay line, strictly per-column
    __shared__ float vsb[2][8][RS];   // double-buffered vs snapshots (+10 halo each side)
    {   // zero halo pads of both parity buffers once
        int j = w >> 6, k = w & 63;
        if (k < 10)      { vsb[0][j][k] = 0.f;       vsb[1][j][k] = 0.f; }
        else if (k < 20) { vsb[0][j][512 + k] = 0.f; vsb[1][j][512 + k] = 0.f; }
    }

    auto diff = [&](int h) -> float {
        float4 l = L4[(size_t)h * W + w];
        if (val) {
            float4 r = R4[(size_t)h * W + wr];
            return fabsf(l.x - r.x) + fabsf(l.y - r.y) + fabsf(l.z - r.z);
        }
        return fabsf(l.x) + fabsf(l.y) + fabsf(l.z);  // r_shift == 0 when invalid
    };

    // Warm-up: rows [h0-10, h0+9] -> ring slots 0..19; slot 20 = row h0-11 (zero).
    float vs = 0.f;
    for (int k = 0; k < 20; ++k) {
        int h = h0 - R + k;
        float dv0 = (h >= 0) ? diff(h) : 0.f;
        ring[k][w] = dv0;
        vs += dv0;
    }
    ring[20][w] = 0.f;

    // fused-argmin state (pixels blk*640 .. blk*640+639)
    const float* cp0 = nullptr; const float* cp1 = nullptr;
    int px0 = 0, px1 = 0;
    float best0 = 3.4e38f, best1 = 3.4e38f;
    int bd0 = 0, bd1 = 0;
    if (FUSE) {
        px0 = blk * 640 + w;
        int b0 = (px0 >= HW) ? 1 : 0;
        cp0 = cprev + (size_t)b0 * D * HW + (px0 - b0 * HW);
        if (w < 128) {
            px1 = blk * 640 + 512 + w;
            int b1 = (px1 >= HW) ? 1 : 0;
            cp1 = cprev + (size_t)b1 * D * HW + (px1 - b1 * HW);
        }
    }

    const int cc = threadIdx.x >> 3;   // phase-2 col-run (0..63)
    const int jj = threadIdx.x & 7;    // phase-2 row slot (0..7)
    float* cp = cost + ((size_t)(b * D + d) * H) * W;

    // prologue: preload superstep 0's diffs
    float dvv[8];
#pragma unroll
    for (int j = 0; j < 8; ++j) {
        int hn = h0 + j + R;
        dvv[j] = (hn < H) ? diff(hn) : 0.f;
    }

    int slot0 = 20;
    int dc = 0;
    for (int ss = 0; ss < 10; ++ss) {
        const int nd = (ss < 4) ? 7 : 6;  // 4*7 + 6*6 = 64 fused d's
        int sl[8];
        float dold[8];
#pragma unroll
        for (int j = 0; j < 8; ++j) { int s2 = slot0 + j; if (s2 >= 21) s2 -= 21; sl[j] = s2; }
#pragma unroll
        for (int j = 0; j < 8; ++j) dold[j] = ring[sl[j]][w];     // 8 indep LDS reads
        float fv0[7], fv1[7];
        if (FUSE) {                                               // indep strided loads
#pragma unroll
            for (int q = 0; q < 7; ++q)
                if (q < nd) fv0[q] = cp0[(size_t)(dc + q) * HW];
            if (w < 128) {
#pragma unroll
                for (int q = 0; q < 7; ++q)
                    if (q < nd) fv1[q] = cp1[(size_t)(dc + q) * HW];
            }
        }
#pragma unroll
        for (int j = 0; j < 8; ++j) ring[sl[j]][w] = dvv[j];      // writes after all reads
        float* vrow = &vsb[ss & 1][0][0];
#pragma unroll
        for (int j = 0; j < 8; ++j) { vs += dvv[j] - dold[j]; vrow[j * RS + 10 + w] = vs; }
        // prefetch next superstep's diffs BEFORE the barrier (overlap with phase 2)
        float dvn[8];
        if (ss < 9) {
#pragma unroll
            for (int j = 0; j < 8; ++j) {
                int hn = h0 + (ss + 1) * 8 + j + R;
                dvn[j] = (hn < H) ? diff(hn) : 0.f;
            }
        } else {
#pragma unroll
            for (int j = 0; j < 8; ++j) dvn[j] = 0.f;
        }
        __syncthreads();
        // phase 2: 28-word window (7x b128) -> 8 horizontally-rolled outputs
        const float* vp = &vsb[ss & 1][jj][8 * cc];
        float wnd[28];
#pragma unroll
        for (int q = 0; q < 7; ++q) {
            float4 v4 = *(const float4*)(vp + 4 * q);
            wnd[4 * q] = v4.x; wnd[4 * q + 1] = v4.y;
            wnd[4 * q + 2] = v4.z; wnd[4 * q + 3] = v4.w;
        }
        float o = 0.f;
#pragma unroll
        for (int k = 0; k < 21; ++k) o += wnd[k];
        float out[8];
        out[0] = o;
#pragma unroll
        for (int k = 1; k < 8; ++k) { o += wnd[20 + k] - wnd[k - 1]; out[k] = o; }
        float* op = cp + (size_t)(h0 + ss * 8 + jj) * W + 8 * cc;
        *(float4*)(op)     = make_float4(out[0], out[1], out[2], out[3]);
        *(float4*)(op + 4) = make_float4(out[4], out[5], out[6], out[7]);
        if (FUSE) {                    // consume fused loads (strict <, ascending d)
#pragma unroll
            for (int q = 0; q < 7; ++q)
                if (q < nd && fv0[q] < best0) { best0 = fv0[q]; bd0 = dc + q; }
            if (w < 128) {
#pragma unroll
                for (int q = 0; q < 7; ++q)
                    if (q < nd && fv1[q] < best1) { best1 = fv1[q]; bd1 = dc + q; }
            }
        }
#pragma unroll
        for (int j = 0; j < 8; ++j) dvv[j] = dvn[j];
        dc += nd;
        slot0 += 8; if (slot0 >= 21) slot0 -= 21;
    }
    if (FUSE) {
        dprev[px0] = (float)bd0;
        if (w < 128) dprev[px1] = (float)bd1;
    }
}

// Stage A: partial argmin over a 16-d chunk, 4 pixels/thread, packed keys
// (bits(cost)&~63)|d -- cost>=0 so uint order == float order; ties pick the
// lowest d (jnp.argmin). NO atomics: plain stores, disjoint ownership.
__global__ void k_aminA(const float* __restrict__ cost, uint4* __restrict__ keys) {
    int idx = blockIdx.x * 256 + threadIdx.x;      // 1280 blocks: 4 chunks x QUADS
    int c = idx / QUADS;
    int q = idx - c * QUADS;
    int b = q / (QUADS / B);
    int ql = q - b * (QUADS / B);
    const float* cp = cost + (size_t)b * D * HW + 4 * ql;
    int d0 = c * 16;
    float4 v = *(const float4*)(cp + (size_t)d0 * HW);
    unsigned kx = (__float_as_uint(v.x) & KM) | (unsigned)d0;
    unsigned ky = (__float_as_uint(v.y) & KM) | (unsigned)d0;
    unsigned kz = (__float_as_uint(v.z) & KM) | (unsigned)d0;
    unsigned kw = (__float_as_uint(v.w) & KM) | (unsigned)d0;
#pragma unroll 4
    for (int k = 1; k < 16; ++k) {
        unsigned d = (unsigned)(d0 + k);
        v = *(const float4*)(cp + (size_t)(d0 + k) * HW);
        unsigned e;
        e = (__float_as_uint(v.x) & KM) | d; kx = (e < kx) ? e : kx;
        e = (__float_as_uint(v.y) & KM) | d; ky = (e < ky) ? e : ky;
        e = (__float_as_uint(v.z) & KM) | d; kz = (e < kz) ? e : kz;
        e = (__float_as_uint(v.w) & KM) | d; kw = (e < kw) ? e : kw;
    }
    keys[idx] = make_uint4(kx, ky, kz, kw);
}

// Stage B: merge 4 chunk-keys per pixel, |argmin - disp0|, per-block partials.
__global__ void k_aminB(const uint4* __restrict__ keys, const float* __restrict__ disp0,
                        float* __restrict__ part) {
    int q = blockIdx.x * 256 + threadIdx.x;        // 320 blocks over QUADS
    uint4 m = keys[q];
#pragma unroll
    for (int c = 1; c < 4; ++c) {
        uint4 kc = keys[(size_t)c * QUADS + q];
        m.x = (kc.x < m.x) ? kc.x : m.x;
        m.y = (kc.y < m.y) ? kc.y : m.y;
        m.z = (kc.z < m.z) ? kc.z : m.z;
        m.w = (kc.w < m.w) ? kc.w : m.w;
    }
    float4 d0 = *(const float4*)(disp0 + (size_t)4 * q);
    float s = fabsf((float)(m.x & 63u) - d0.x) + fabsf((float)(m.y & 63u) - d0.y) +
              fabsf((float)(m.z & 63u) - d0.z) + fabsf((float)(m.w & 63u) - d0.w);
    __shared__ float sm[256];
    sm[threadIdx.x] = s;
    __syncthreads();
    for (int off = 128; off; off >>= 1) {
        if (threadIdx.x < off) sm[threadIdx.x] += sm[threadIdx.x + off];
        __syncthreads();
    }
    if (!threadIdx.x) part[blockIdx.x] = sm[0];
}

// Fallback-path standalone argmin (4 px/thread, float4).
__global__ void k_amin(const float* __restrict__ cost, float* __restrict__ disp) {
    int blk = blockIdx.x;
    int b = (blk * 1024 >= HW) ? 1 : 0;
    int hw0 = blk * 1024 - b * HW + threadIdx.x * 4;
    const float* cp = cost + (size_t)b * D * HW + hw0;
    float4 v = *(const float4*)cp;
    float bb[4] = {v.x, v.y, v.z, v.w};
    int bd[4] = {0, 0, 0, 0};
    for (int d = 1; d < D; ++d) {
        v = *(const float4*)(cp + (size_t)d * HW);
        if (v.x < bb[0]) { bb[0] = v.x; bd[0] = d; }
        if (v.y < bb[1]) { bb[1] = v.y; bd[1] = d; }
        if (v.z < bb[2]) { bb[2] = v.z; bd[2] = d; }
        if (v.w < bb[3]) { bb[3] = v.w; bd[3] = d; }
    }
    *(float4*)(disp + (size_t)blk * 1024 + threadIdx.x * 4) =
        make_float4((float)bd[0], (float)bd[1], (float)bd[2], (float)bd[3]);
}

__global__ void k_red2(const float* __restrict__ part, float* __restrict__ out,
                       int nb, float inv) {
    __shared__ float sm[256];
    int tid = threadIdx.x;
    float s = 0.f;
    for (int i = tid; i < nb; i += 256) s += part[i];
    sm[tid] = s;
    __syncthreads();
    for (int off = 128; off; off >>= 1) {
        if (tid < off) sm[tid] += sm[tid + off];
        __syncthreads();
    }
    if (!tid) out[0] = sm[0] * inv;
}

extern "C" void kernel_launch(void* const* d_in, const int* in_sizes, int n_in,
                              void* d_out, int out_size, void* d_ws, size_t ws_size,
                              hipStream_t stream) {
    const float* x  = (const float*)d_in[0];
    const float* gt = (const float*)d_in[1];

    constexpr size_t NRM_F4 = (size_t)2 * B * 2 * HW;        // float4 count (21.0 MB)
    constexpr size_t COST_F = (size_t)B * D * HW;            // f32 count (83.9 MB)
    constexpr int NRM_BLKS  = (2 * B * (HW / 4) + 127) / 128;

    float4* nrm4 = (float4*)d_ws;
    float* cost0 = (float*)(nrm4 + NRM_F4);

    size_t need_primary = NRM_F4 * 16 + 2 * COST_F * 4 +
                          (size_t)4 * QUADS * 16 + (size_t)(B * HW + 4096) * 4;

    k_norm<<<NRM_BLKS, 128, 0, stream>>>(x, gt, nrm4);

    if (ws_size >= need_primary) {
        float* cost1 = cost0 + COST_F;
        uint4* kd    = (uint4*)(cost1 + COST_F);
        float* disp0 = (float*)(kd + (size_t)4 * QUADS);
        float* part  = disp0 + (size_t)B * HW;
        k_cost<false><<<B * NSEG * D, 512, 0, stream>>>(nrm4, cost0, nullptr, nullptr, 0);
        k_cost<true><<<B * NSEG * D, 512, 0, stream>>>(nrm4, cost1, cost0, disp0, 1);
        k_aminA<<<4 * QUADS / 256, 256, 0, stream>>>(cost1, kd);
        k_aminB<<<QUADS / 256, 256, 0, stream>>>(kd, disp0, part);
        k_red2<<<1, 256, 0, stream>>>(part, (float*)d_out, QUADS / 256, 1.f / (float)(B * HW));
    } else {
        float* disp0 = cost0 + COST_F;
        uint4* kd    = (uint4*)(disp0 + (size_t)B * HW);
        float* part  = (float*)(kd + (size_t)4 * QUADS);
        k_cost<false><<<B * NSEG * D, 512, 0, stream>>>(nrm4, cost0, nullptr, nullptr, 0);
        k_amin<<<B * HW / 1024, 256, 0, stream>>>(cost0, disp0);
        k_cost<false><<<B * NSEG * D, 512, 0, stream>>>(nrm4, cost0, nullptr, nullptr, 1);
        k_aminA<<<4 * QUADS / 256, 256, 0, stream>>>(cost0, kd);
        k_aminB<<<QUADS / 256, 256, 0, stream>>>(kd, disp0, part);
        k_red2<<<1, 256, 0, stream>>>(part, (float*)d_out, QUADS / 256, 1.f / (float)(B * HW));
    }
}